// Round 8
// baseline (1870.105 us; speedup 1.0000x reference)
//
#include <hip/hip_runtime.h>

#define STR 260          // bH/bP row stride (floats)
#define QTS 20           // qT row stride (floats): 16 data + 4 pad, rows 16B-aligned
#define NGRAPH 512

typedef float float4v __attribute__((ext_vector_type(4)));

static __device__ __forceinline__ float4v ld4(const float* p){ return *(const float4v*)p; }
static __device__ __forceinline__ void st4(float* p, float4v v){ *(float4v*)p = v; }

// ---- C[16][256] = act(A[16][256] @ Bg[256][256] + bias), barrier-free ----
// thread: rows 2*(tid>>5)..+2, cols (tid&31)*8..+8. A via broadcast ds_read_b128,
// B from global (L1/L2-hot) with distance-4 register prefetch. acc = 16 regs.
template<bool RELU, bool HASBIAS>
__device__ __forceinline__ void dgemm16(const float* __restrict__ A,
                                        const float* __restrict__ Bg,
                                        const float* __restrict__ bias,
                                        float* __restrict__ C, int tid)
{
    const int r0 = (tid >> 5) * 2;
    const int c0 = (tid & 31) * 8;
    const float* arow0 = A + r0 * STR;
    const float* arow1 = arow0 + STR;
    const float* bcol  = Bg + c0;

    float acc0[8], acc1[8];
#pragma unroll
    for (int c = 0; c < 8; ++c) { acc0[c] = 0.f; acc1[c] = 0.f; }

    float4v bs[4][2];
#pragma unroll
    for (int j = 0; j < 4; ++j) { bs[j][0] = ld4(bcol + j*256); bs[j][1] = ld4(bcol + j*256 + 4); }
    float4v a0 = ld4(arow0), a1 = ld4(arow1);

    for (int ks = 0; ks < 64; ++ks) {
        const float4v ca0 = a0, ca1 = a1;
        if (ks < 63) { a0 = ld4(arow0 + (ks+1)*4); a1 = ld4(arow1 + (ks+1)*4); }
#pragma unroll
        for (int kq = 0; kq < 4; ++kq) {
            const int k = ks*4 + kq;
            const float4v cb0 = bs[kq][0], cb1 = bs[kq][1];
            if (k < 252) {                       // refill slot with k+4 (same slot index)
                const float* nb = bcol + (k+4)*256;
                bs[kq][0] = ld4(nb); bs[kq][1] = ld4(nb + 4);
            }
            const float av0 = ca0[kq], av1 = ca1[kq];
            float b[8] = {cb0[0],cb0[1],cb0[2],cb0[3],cb1[0],cb1[1],cb1[2],cb1[3]};
#pragma unroll
            for (int c = 0; c < 8; ++c) {
                acc0[c] = fmaf(av0, b[c], acc0[c]);
                acc1[c] = fmaf(av1, b[c], acc1[c]);
            }
        }
    }
    float o0[8], o1[8];
#pragma unroll
    for (int c = 0; c < 8; ++c) {
        float v0 = acc0[c], v1 = acc1[c];
        if (HASBIAS) { const float bb = bias[c0+c]; v0 += bb; v1 += bb; }
        if (RELU)    { v0 = fmaxf(v0, 0.f); v1 = fmaxf(v1, 0.f); }
        o0[c] = v0; o1[c] = v1;
    }
    st4(C + r0*STR + c0,         (float4v){o0[0],o0[1],o0[2],o0[3]});
    st4(C + r0*STR + c0 + 4,     (float4v){o0[4],o0[5],o0[6],o0[7]});
    st4(C + (r0+1)*STR + c0,     (float4v){o1[0],o1[1],o1[2],o1[3]});
    st4(C + (r0+1)*STR + c0 + 4, (float4v){o1[4],o1[5],o1[6],o1[7]});
}

// ---- fused p/q: Cp = A@Bp (row-major), qT = (A@Bq + biasq)^T, barrier-free ----
__device__ __forceinline__ void dgemm16_pq(const float* __restrict__ A,
                                           const float* __restrict__ Bp,
                                           const float* __restrict__ Bq,
                                           const float* __restrict__ biasq,
                                           float* __restrict__ Cp,
                                           float* __restrict__ qT, int tid)
{
    const int r0 = (tid >> 5) * 2;
    const int c0 = (tid & 31) * 8;
    const float* arow0 = A + r0 * STR;
    const float* arow1 = arow0 + STR;
    const float* bpc = Bp + c0;
    const float* bqc = Bq + c0;

    float ap0[8], ap1[8], aq0[8], aq1[8];
#pragma unroll
    for (int c = 0; c < 8; ++c) { ap0[c]=0.f; ap1[c]=0.f; aq0[c]=0.f; aq1[c]=0.f; }

    float4v bps[2][2], bqs[2][2];
    bps[0][0]=ld4(bpc);     bps[0][1]=ld4(bpc+4);
    bps[1][0]=ld4(bpc+256); bps[1][1]=ld4(bpc+256+4);
    bqs[0][0]=ld4(bqc);     bqs[0][1]=ld4(bqc+4);
    bqs[1][0]=ld4(bqc+256); bqs[1][1]=ld4(bqc+256+4);
    float4v a0 = ld4(arow0), a1 = ld4(arow1);

    for (int ks = 0; ks < 64; ++ks) {
        const float4v ca0 = a0, ca1 = a1;
        if (ks < 63) { a0 = ld4(arow0 + (ks+1)*4); a1 = ld4(arow1 + (ks+1)*4); }
#pragma unroll
        for (int kq = 0; kq < 4; ++kq) {
            const int k = ks*4 + kq;
            const float4v cp0 = bps[kq&1][0], cp1 = bps[kq&1][1];
            const float4v cq0 = bqs[kq&1][0], cq1 = bqs[kq&1][1];
            if (k < 254) {                      // dist-2 refill, both streams
                const float* np = bpc + (k+2)*256;
                const float* nq = bqc + (k+2)*256;
                bps[kq&1][0] = ld4(np); bps[kq&1][1] = ld4(np+4);
                bqs[kq&1][0] = ld4(nq); bqs[kq&1][1] = ld4(nq+4);
            }
            const float av0 = ca0[kq], av1 = ca1[kq];
            float bp[8] = {cp0[0],cp0[1],cp0[2],cp0[3],cp1[0],cp1[1],cp1[2],cp1[3]};
            float bq[8] = {cq0[0],cq0[1],cq0[2],cq0[3],cq1[0],cq1[1],cq1[2],cq1[3]};
#pragma unroll
            for (int c = 0; c < 8; ++c) {
                ap0[c] = fmaf(av0, bp[c], ap0[c]);
                ap1[c] = fmaf(av1, bp[c], ap1[c]);
                aq0[c] = fmaf(av0, bq[c], aq0[c]);
                aq1[c] = fmaf(av1, bq[c], aq1[c]);
            }
        }
    }
    st4(Cp + r0*STR + c0,         (float4v){ap0[0],ap0[1],ap0[2],ap0[3]});
    st4(Cp + r0*STR + c0 + 4,     (float4v){ap0[4],ap0[5],ap0[6],ap0[7]});
    st4(Cp + (r0+1)*STR + c0,     (float4v){ap1[0],ap1[1],ap1[2],ap1[3]});
    st4(Cp + (r0+1)*STR + c0 + 4, (float4v){ap1[4],ap1[5],ap1[6],ap1[7]});
#pragma unroll
    for (int c = 0; c < 8; ++c) {              // q stored transposed: qT[k][j]
        const float bb = biasq[c0+c];
        qT[(c0+c)*QTS + r0]     = aq0[c] + bb;
        qT[(c0+c)*QTS + r0 + 1] = aq1[c] + bb;
    }
}

__global__ __launch_bounds__(256, 3)   // cap VGPR ~168: between the 128-spill and 256-pairing cliffs
void fcgn_kernel(const float* __restrict__ towers, const float* __restrict__ We,
                 const float* __restrict__ be,  const float* __restrict__ Wm1,
                 const float* __restrict__ bm1, const float* __restrict__ Wm2,
                 const float* __restrict__ bm2, const float* __restrict__ Wu1,
                 const float* __restrict__ bu1, const float* __restrict__ Wu2,
                 const float* __restrict__ bu2, const float* __restrict__ Wo1,
                 const float* __restrict__ bo1, const float* __restrict__ Wo2,
                 const float* __restrict__ bo2, const int* __restrict__ kPtr,
                 float* __restrict__ out)
{
    __shared__ alignas(16) float bH[16*STR];    // h -> x -> h'
    __shared__ alignas(16) float bP[16*STR];    // p / y
    __shared__ alignas(16) float qT[256*QTS];   // q transposed: qT[k][j]
    __shared__ float TW[224];
    __shared__ float LG[16];

    const int gid = blockIdx.x;
    const int tid = threadIdx.x;

    if (tid < 224) TW[tid] = towers[gid*224 + tid];
    __syncthreads();

    // ---- encoder: h = towers @ We + be ----
    {
        const int r = tid >> 4, u = tid & 15;
        for (int cc = 0; cc < 16; ++cc) {
            const int c = cc*16 + u;
            float sum = be[c];
#pragma unroll
            for (int f = 0; f < 14; ++f)
                sum = fmaf(TW[r*14 + f], We[f*256 + c], sum);
            bH[r*STR + c] = sum;
        }
    }
    __syncthreads();

    int kk = kPtr[0];
    if (kk < 0) kk = 0;
    if (kk > 8) kk = 8;   // defensive: garbage k must not hang the GPU

    // ---- edge-phase mapping: 16 rowgroups x 4 pair-rows, 16 colgroups x 16 cols ----
    const int e_rg = tid >> 4;          // 0..15
    const int e_cg = tid & 15;          // 0..15
    const int cb   = e_cg * 16;
    const int jb   = (e_rg & 3) * 4;    // this thread's 4 receiver nodes
    const int iSub = e_rg >> 2;         // sender index within chunk (i = ch*4 + iSub)

    for (int rnd = 0; rnd < kk; ++rnd) {
        dgemm16_pq(bH, Wm1, Wm1 + 256*256, bm1, bP, qT, tid);
        __syncthreads();                // p, qT visible; bH/bP/qT read-only below

        // ---- edge GEMM: 256 pairs x 256 cols, 4 chunks x 32 ksteps, ZERO barriers ----
        float acc[4][16];
#pragma unroll
        for (int m = 0; m < 4; ++m)
#pragma unroll
            for (int c = 0; c < 16; ++c) acc[m][c] = 0.f;

        const float* prow0 = bP + iSub*STR;
        float4v p0 = ld4(prow0), p1 = ld4(prow0 + 4);
        float4v bs[2][4];
#pragma unroll
        for (int j = 0; j < 4; ++j) {
            bs[0][j] = ld4(Wm2 + 0*256 + cb + j*4);
            bs[1][j] = ld4(Wm2 + 1*256 + cb + j*4);
        }
        float4v qv = ld4(qT + 0*QTS + jb);

        for (int g = 0; g < 128; ++g) {
            const int ch = g >> 5;
            const int ks = (g & 31) * 8;
            float4v pn0, pn1;
            if (g < 127) {              // prefetch next iteration's p-row segment
                const int gn = g + 1;
                const int iN = (gn >> 5)*4 + iSub;
                const int ksN = (gn & 31)*8;
                pn0 = ld4(bP + iN*STR + ksN);
                pn1 = ld4(bP + iN*STR + ksN + 4);
            } else { pn0 = p0; pn1 = p1; }
#pragma unroll
            for (int kt = 0; kt < 8; ++kt) {
                const int k = ks + kt;
                const float4v cb0 = bs[kt&1][0], cb1 = bs[kt&1][1],
                              cb2 = bs[kt&1][2], cb3 = bs[kt&1][3];
                const int kpf = (k + 2) & 255;      // dist-2 refill (wraps into next chunk)
#pragma unroll
                for (int j = 0; j < 4; ++j)
                    bs[kt&1][j] = ld4(Wm2 + kpf*256 + cb + j*4);
                const float4v qcur = qv;
                qv = ld4(qT + ((k+1)&255)*QTS + jb);
                const float pv = (kt < 4) ? p0[kt] : p1[kt-4];
                float av[4];
#pragma unroll
                for (int m = 0; m < 4; ++m) av[m] = fmaxf(pv + qcur[m], 0.f);
                float b[16] = {cb0[0],cb0[1],cb0[2],cb0[3], cb1[0],cb1[1],cb1[2],cb1[3],
                               cb2[0],cb2[1],cb2[2],cb2[3], cb3[0],cb3[1],cb3[2],cb3[3]};
#pragma unroll
                for (int m = 0; m < 4; ++m)
#pragma unroll
                    for (int c = 0; c < 16; ++c)
                        acc[m][c] = fmaf(av[m], b[c], acc[m][c]);
            }
            if ((g & 31) == 31) {       // chunk epilogue: mask, reduce over 4 rowgroups, RMW x into bH
                const int iG = ch*4 + iSub;
                float part[16];
#pragma unroll
                for (int c = 0; c < 16; ++c) part[c] = 0.f;
#pragma unroll
                for (int m = 0; m < 4; ++m) {
                    const float msk = (jb + m == iG) ? 0.f : 1.f;
#pragma unroll
                    for (int c = 0; c < 16; ++c)
                        part[c] += msk * fmaxf(acc[m][c] + bm2[cb+c], 0.f);
                }
#pragma unroll
                for (int c = 0; c < 16; ++c) {
                    part[c] += __shfl_xor(part[c], 16);
                    part[c] += __shfl_xor(part[c], 32);
                }
                if ((e_rg & 3) == 0) {  // unique owner per (iG, 16-col block): plain RMW
#pragma unroll
                    for (int v = 0; v < 4; ++v) {
                        float4v h = ld4(bH + iG*STR + cb + v*4);
#pragma unroll
                        for (int c = 0; c < 4; ++c) h[c] += part[v*4+c];
                        st4(bH + iG*STR + cb + v*4, h);
                    }
                }
#pragma unroll
                for (int m = 0; m < 4; ++m)
#pragma unroll
                    for (int c = 0; c < 16; ++c) acc[m][c] = 0.f;
            }
            p0 = pn0; p1 = pn1;
        }
        __syncthreads();                // x ready in bH; bP free

        dgemm16<true ,true>(bH, Wu1, bu1, bP, tid);   // y  -> bP
        __syncthreads();
        dgemm16<false,true>(bP, Wu2, bu2, bH, tid);   // h' -> bH
        __syncthreads();
    }

    // ---- output head ----
    dgemm16<true,true>(bH, Wo1, bo1, bP, tid);        // y2 -> bP
    __syncthreads();
    {
        const int r = tid >> 4, u = tid & 15;
        float partial = 0.f;
#pragma unroll
        for (int t2 = 0; t2 < 16; ++t2)
            partial = fmaf(bP[r*STR + u*16 + t2], Wo2[u*16 + t2], partial);
        partial += __shfl_xor(partial, 1);
        partial += __shfl_xor(partial, 2);
        partial += __shfl_xor(partial, 4);
        partial += __shfl_xor(partial, 8);
        if (u == 0) LG[r] = partial + bo2[0];
    }
    __syncthreads();
    if (tid == 0) {
        float pr = 1.f;
#pragma unroll
        for (int i = 0; i < 16; ++i)
            pr *= 1.f / (1.f + expf(-LG[i]));
        out[gid] = pr;
    }
}

extern "C" void kernel_launch(void* const* d_in, const int* in_sizes, int n_in,
                              void* d_out, int out_size, void* d_ws, size_t ws_size,
                              hipStream_t stream)
{
    (void)in_sizes; (void)n_in; (void)out_size; (void)d_ws; (void)ws_size;
    fcgn_kernel<<<dim3(NGRAPH), dim3(256), 0, stream>>>(
        (const float*)d_in[0],  (const float*)d_in[1],  (const float*)d_in[2],
        (const float*)d_in[3],  (const float*)d_in[4],  (const float*)d_in[5],
        (const float*)d_in[6],  (const float*)d_in[7],  (const float*)d_in[8],
        (const float*)d_in[9],  (const float*)d_in[10], (const float*)d_in[11],
        (const float*)d_in[12], (const float*)d_in[13], (const float*)d_in[14],
        (const int*)d_in[15],   (float*)d_out);
}

// Round 9
// 1591.569 us; speedup vs baseline: 1.1750x; 1.1750x over previous
//
#include <hip/hip_runtime.h>

#define STR 260          // bH/bP/bQ row stride (floats); 260%32=4 -> 2-way column reads
#define NGRAPH 512

typedef float float4v __attribute__((ext_vector_type(4)));
typedef float float2v __attribute__((ext_vector_type(2)));

static __device__ __forceinline__ float4v ld4(const float* p){ return *(const float4v*)p; }
static __device__ __forceinline__ void st4(float* p, float4v v){ *(float4v*)p = v; }
static __device__ __forceinline__ void st2(float* p, float2v v){ *(float2v*)p = v; }

// ---- 16x256x256 GEMM, 512 threads: C = act(A @ Bg + bias) ----
// split-K-4 over lane quads, 4x8 tiles (32 accs), k-step 8, B from global with
// distance-2 register rotation, A^T double-buffered in LDS. ~80 live VGPRs.
template<bool RELU, bool HASBIAS>
__device__ __forceinline__ void sgemm16(const float* __restrict__ A,
                                        const float* __restrict__ Bg,
                                        const float* __restrict__ bias,
                                        float* __restrict__ C,
                                        float* __restrict__ AtS,
                                        int tid)
{
    const int s  = tid & 3;            // K-slice (64 k each)
    const int cg = (tid >> 2) & 31;    // 8 cols
    const int rg = tid >> 7;           // 4 rows (rg*4..rg*4+3)
    const int w_kt = tid & 7, w_s = (tid >> 3) & 3, w_r = tid >> 5;   // stage map (1 elem/thread)
    const int idxw = w_kt*84 + w_s*21 + w_r;
    const int rB   = w_r*STR + w_s*64 + w_kt;

    __syncthreads();                   // A (LDS) written by previous phase; AtS reads done
    AtS[idxw] = A[rB];                 // stage step 0
    __syncthreads();

    float acc[4][8];
#pragma unroll
    for (int m=0;m<4;++m)
#pragma unroll
        for (int c=0;c<8;++c) acc[m][c]=0.f;

    const float* bcol = Bg + s*64*256 + cg*8;
    float4v bs0 = ld4(bcol),       bs1 = ld4(bcol + 4);        // slice k-row 0
    float4v bt0 = ld4(bcol + 256), bt1 = ld4(bcol + 256 + 4);  // slice k-row 1

    for (int step = 0; step < 8; ++step) {
        const float* cur = AtS + (step&1)*672;
        float nxt = 0.f;
        if (step < 7) nxt = A[rB + (step+1)*8];
#pragma unroll
        for (int kt = 0; kt < 8; ++kt) {
            float4v cb0, cb1;
            if (kt & 1) { cb0 = bt0; cb1 = bt1; } else { cb0 = bs0; cb1 = bs1; }
            const int kNext = step*8 + kt + 2;                 // dist-2 refill
            if (kNext < 64) {
                const float* nb = bcol + kNext*256;
                if (kt & 1) { bt0 = ld4(nb); bt1 = ld4(nb + 4); }
                else        { bs0 = ld4(nb); bs1 = ld4(nb + 4); }
            }
            const float4v a4 = ld4(cur + kt*84 + s*21 + rg*4); // 4 rows, broadcast x16
            float b[8] = {cb0[0],cb0[1],cb0[2],cb0[3],cb1[0],cb1[1],cb1[2],cb1[3]};
#pragma unroll
            for (int m=0;m<4;++m)
#pragma unroll
                for (int c=0;c<8;++c) acc[m][c] = fmaf(a4[m], b[c], acc[m][c]);
        }
        if (step < 7) AtS[((step+1)&1)*672 + idxw] = nxt;
        __syncthreads();
    }
    // reduce the 4 K-slices (lane quads)
#pragma unroll
    for (int m=0;m<4;++m)
#pragma unroll
        for (int c=0;c<8;++c) {
            float v = acc[m][c];
            v += __shfl_xor(v,1);
            v += __shfl_xor(v,2);
            acc[m][c] = v;
        }
    if (s == 0) {
        const int c0 = cg*8;
#pragma unroll
        for (int m=0;m<4;++m) {
            float o[8];
#pragma unroll
            for (int c=0;c<8;++c) {
                float v = acc[m][c];
                if (HASBIAS) v += bias[c0+c];
                if (RELU)    v = fmaxf(v,0.f);
                o[c] = v;
            }
            st4(C + (rg*4+m)*STR + c0,     (float4v){o[0],o[1],o[2],o[3]});
            st4(C + (rg*4+m)*STR + c0 + 4, (float4v){o[4],o[5],o[6],o[7]});
        }
    }
    // no trailing sync; every consumer phase begins with __syncthreads()
}

__global__ __launch_bounds__(512, 4)   // 4 waves/EU -> VGPR cap 128; LDS 80.9KB -> 2 blocks/CU
void fcgn_kernel(const float* __restrict__ towers, const float* __restrict__ We,
                 const float* __restrict__ be,  const float* __restrict__ Wm1,
                 const float* __restrict__ bm1, const float* __restrict__ Wm2,
                 const float* __restrict__ bm2, const float* __restrict__ Wu1,
                 const float* __restrict__ bu1, const float* __restrict__ Wu2,
                 const float* __restrict__ bu2, const float* __restrict__ Wo1,
                 const float* __restrict__ bo1, const float* __restrict__ Wo2,
                 const float* __restrict__ bo2, const int* __restrict__ kPtr,
                 float* __restrict__ out)
{
    __shared__ alignas(16) float bH[16*STR];      // h -> x -> h'
    __shared__ alignas(16) float bP[16*STR];      // p / y
    __shared__ alignas(16) float bQ[16*STR];      // q
    __shared__ alignas(16) float BTB[2][8*256];   // edge Wm2 tile (XOR-swizzled 16B slots)
    __shared__ alignas(16) float ATB[2][8*128];   // edge relu(p_i+q_j)^T tile (128 pair-rows)
    __shared__ alignas(16) float AtS[2*672];      // sgemm A^T tiles
    __shared__ float TW[224];
    __shared__ float LG[16];

    const int gid = blockIdx.x;
    const int tid = threadIdx.x;

    if (tid < 224) TW[tid] = towers[gid*224 + tid];
    __syncthreads();

    // ---- encoder: h = towers @ We + be ----
    {
        const int r = tid >> 5, u = tid & 31;
        for (int cc = 0; cc < 8; ++cc) {
            const int c = cc*32 + u;
            float sum = be[c];
#pragma unroll
            for (int f = 0; f < 14; ++f)
                sum = fmaf(TW[r*14 + f], We[f*256 + c], sum);
            bH[r*STR + c] = sum;
        }
    }

    int kk = kPtr[0];
    if (kk < 0) kk = 0;
    if (kk > 8) kk = 8;   // defensive: garbage k must not hang the GPU

    // ---- edge-phase thread mappings (8x8 tiles, 128-row chunks, 512 threads) ----
    const int e_rg = tid >> 5;     // 16 rowgroups of 8 pair-rows
    const int e_cg = tid & 31;     // 32 colgroups of 8 cols
    const int sl0 = 2*e_cg, sl1 = 2*e_cg + 1;
    const int off0 = (sl0 ^ ((sl0>>3)&7))*4;     // XOR-swizzled 16B-slot offsets (floats)
    const int off1 = (sl1 ^ ((sl1>>3)&7))*4;
    const int sb_kt   = tid >> 6;                 // B stage: k-row, 1 ld4/thread
    const int sb_sl   = tid & 63;
    const int sb_phys = (sb_sl ^ ((sb_sl>>3)&7))*4;
    const int sa_kt   = tid >> 6;                 // A^T stage: k-row, pair-rows r0,r0+1
    const int sa_r0   = (tid & 63)*2;             // 0..126
    const int sa_j0   = sa_r0 & 15;               // even
    const int sa_i    = sa_r0 >> 4;               // 0..7
    const int ep_iL   = e_rg >> 1;                // epilogue: chunk-local sender 0..7
    const int ep_jB   = (e_rg & 1)*8;

    for (int rnd = 0; rnd < kk; ++rnd) {
        // p = h @ Wm1[:256] ; q = h @ Wm1[256:] + bm1
        sgemm16<false,false>(bH, Wm1,           nullptr, bP, AtS, tid);
        sgemm16<false,true >(bH, Wm1 + 256*256, bm1,     bQ, AtS, tid);

        // ---- edge GEMM: 256 pair-rows x 256 cols; 2 chunks x 32 k-steps of 8 ----
        __syncthreads();               // p,q visible
        {   // prologue: stage g=0 (ch=0, ks=0)
            st4(&BTB[0][sb_kt*256 + sb_phys], ld4(Wm2 + sb_kt*256 + sb_sl*4));
            const float pv = bP[sa_i*STR + sa_kt];
            const float v0 = fmaxf(pv + bQ[ sa_j0   *STR + sa_kt], 0.f);
            const float v1 = fmaxf(pv + bQ[(sa_j0+1)*STR + sa_kt], 0.f);
            st2(&ATB[0][sa_kt*128 + sa_r0], (float2v){v0, v1});
        }
        __syncthreads();

        float eacc[8][8];
#pragma unroll
        for (int m=0;m<8;++m)
#pragma unroll
            for (int c=0;c<8;++c) eacc[m][c]=0.f;

        for (int g = 0; g < 64; ++g) {
            const int buf = g & 1;
            const int ch = g >> 5, step = g & 31;
            // T14: issue next-tile loads into registers BEFORE the FMA block
            float4v pb0;
            float pa0 = 0.f, pa1 = 0.f;
            const int gn = g + 1, bufn = gn & 1;
            if (g < 63) {
                const int chn = gn >> 5, ksn = (gn & 31)*8;
                pb0 = ld4(Wm2 + (ksn + sb_kt)*256 + sb_sl*4);
                const int k0 = ksn + sa_kt;
                const float pv = bP[(chn*8 + sa_i)*STR + k0];
                pa0 = fmaxf(pv + bQ[ sa_j0   *STR + k0], 0.f);
                pa1 = fmaxf(pv + bQ[(sa_j0+1)*STR + k0], 0.f);
            }
            // compute 8 kt x (8x8) FMA on buf — covers the L2 latency of pb0
#pragma unroll
            for (int kt = 0; kt < 8; ++kt) {
                const float* ap = &ATB[buf][kt*128 + e_rg*8];
                const float* bb = &BTB[buf][kt*256];
                float4v a0 = ld4(ap), a1 = ld4(ap+4);
                float4v b0 = ld4(bb + off0), b1 = ld4(bb + off1);
                float a[8] = {a0[0],a0[1],a0[2],a0[3],a1[0],a1[1],a1[2],a1[3]};
                float b[8] = {b0[0],b0[1],b0[2],b0[3],b1[0],b1[1],b1[2],b1[3]};
#pragma unroll
                for (int m=0;m<8;++m)
#pragma unroll
                    for (int c=0;c<8;++c) eacc[m][c] = fmaf(a[m], b[c], eacc[m][c]);
            }
            if (step == 31) {
                // epilogue: relu(acc+bm2), mask j!=i, pair-reduce, accumulate x into bH
                const int iG = ch*8 + ep_iL;
                const int cb = e_cg*8;
                float part[8];
#pragma unroll
                for (int c=0;c<8;++c) part[c]=0.f;
#pragma unroll
                for (int m=0;m<8;++m) {
                    const float msk = (ep_jB + m == iG) ? 0.f : 1.f;
#pragma unroll
                    for (int c=0;c<8;++c)
                        part[c] += msk * fmaxf(eacc[m][c] + bm2[cb+c], 0.f);
                }
#pragma unroll
                for (int c=0;c<8;++c) part[c] += __shfl_xor(part[c], 32);
                if ((e_rg & 1) == 0) {      // unique owner per (iG, col-octet): plain RMW
                    float4v h0 = ld4(bH + iG*STR + cb);
                    float4v h1 = ld4(bH + iG*STR + cb + 4);
#pragma unroll
                    for (int c=0;c<4;++c){ h0[c]+=part[c]; h1[c]+=part[c+4]; }
                    st4(bH + iG*STR + cb,     h0);
                    st4(bH + iG*STR + cb + 4, h1);
                }
#pragma unroll
                for (int m=0;m<8;++m)
#pragma unroll
                    for (int c=0;c<8;++c) eacc[m][c]=0.f;
            }
            if (g < 63) {   // write prefetched tile; vmcnt drain lands AFTER the FMAs
                st4(&BTB[bufn][sb_kt*256 + sb_phys], pb0);
                st2(&ATB[bufn][sa_kt*128 + sa_r0], (float2v){pa0, pa1});
            }
            __syncthreads();
        }

        // ---- node update: h' = relu(x@Wu1+bu1)@Wu2 + bu2 ----
        sgemm16<true ,true>(bH, Wu1, bu1, bP, AtS, tid);   // y  -> bP
        sgemm16<false,true>(bP, Wu2, bu2, bH, AtS, tid);   // h' -> bH
    }

    // ---- output head ----
    sgemm16<true,true>(bH, Wo1, bo1, bP, AtS, tid);        // y2 -> bP
    __syncthreads();
    {
        const int r = tid >> 5, u = tid & 31;
        float partial = 0.f;
#pragma unroll
        for (int t2 = 0; t2 < 8; ++t2)
            partial = fmaf(bP[r*STR + u*8 + t2], Wo2[u*8 + t2], partial);
        partial += __shfl_xor(partial, 1);
        partial += __shfl_xor(partial, 2);
        partial += __shfl_xor(partial, 4);
        partial += __shfl_xor(partial, 8);
        partial += __shfl_xor(partial, 16);
        if (u == 0) LG[r] = partial + bo2[0];
    }
    __syncthreads();
    if (tid == 0) {
        float pr = 1.f;
#pragma unroll
        for (int i = 0; i < 16; ++i)
            pr *= 1.f / (1.f + expf(-LG[i]));
        out[gid] = pr;
    }
}

extern "C" void kernel_launch(void* const* d_in, const int* in_sizes, int n_in,
                              void* d_out, int out_size, void* d_ws, size_t ws_size,
                              hipStream_t stream)
{
    (void)in_sizes; (void)n_in; (void)out_size; (void)d_ws; (void)ws_size;
    fcgn_kernel<<<dim3(NGRAPH), dim3(512), 0, stream>>>(
        (const float*)d_in[0],  (const float*)d_in[1],  (const float*)d_in[2],
        (const float*)d_in[3],  (const float*)d_in[4],  (const float*)d_in[5],
        (const float*)d_in[6],  (const float*)d_in[7],  (const float*)d_in[8],
        (const float*)d_in[9],  (const float*)d_in[10], (const float*)d_in[11],
        (const float*)d_in[12], (const float*)d_in[13], (const float*)d_in[14],
        (const int*)d_in[15],   (float*)d_out);
}